// Round 7
// baseline (779.546 us; speedup 1.0000x reference)
//
#include <hip/hip_runtime.h>

// GraphConvBlock, v7: ONE persistent kernel (aux + 7 conv stages) with
// device-scope grid barriers. Inner conv structure = v6 (bf16 MFMA implicit
// GEMM, K-split wave pairs, 3-deep async weight LDS pipeline, counted vmcnt).
// Grid 256 blocks (1/CU, LDS 150.5KB) x 512 thr. Barriers: global after setup,
// per-image (32 blocks, XCD-local) between conv stages.

typedef __bf16 bf16x8 __attribute__((ext_vector_type(8)));
typedef float f32x4 __attribute__((ext_vector_type(4)));

union U4 { uint4 u; bf16x8 b; };

__device__ inline unsigned pk_bf16(float lo, float hi) {
  unsigned r;
  asm volatile("v_cvt_pk_bf16_f32 %0, %1, %2" : "=v"(r) : "v"(lo), "v"(hi));
  return r;
}

__device__ inline unsigned addpk(unsigned a, unsigned b) {
  float alo = __builtin_bit_cast(float, a << 16);
  float ahi = __builtin_bit_cast(float, a & 0xFFFF0000u);
  float blo = __builtin_bit_cast(float, b << 16);
  float bhi = __builtin_bit_cast(float, b & 0xFFFF0000u);
  return pk_bf16(alo + blo, ahi + bhi);
}

__device__ inline uint4 addpk4(uint4 a, uint4 b) {
  return make_uint4(addpk(a.x, b.x), addpk(a.y, b.y), addpk(a.z, b.z), addpk(a.w, b.w));
}

__device__ __forceinline__ void gload16(const unsigned* g, unsigned* l) {
  __builtin_amdgcn_global_load_lds(
      (const __attribute__((address_space(1))) unsigned*)(g),
      (__attribute__((address_space(3))) unsigned*)(l), 16, 0, 0);
}

template <int N>
__device__ __forceinline__ void waitcnt_vm() {
  if constexpr (N == 0) asm volatile("s_waitcnt vmcnt(0)" ::: "memory");
  else if constexpr (N == 1) asm volatile("s_waitcnt vmcnt(1)" ::: "memory");
  else asm volatile("s_waitcnt vmcnt(2)" ::: "memory");
}

#define WB_WORDS 479232

// ---- device-scope grid barrier (sense-reversing generation) -----------------
__device__ __forceinline__ void grid_bar(unsigned* c, unsigned* g, unsigned nblk) {
  __threadfence();  // release: drain stores, write back L2
  __syncthreads();
  if (threadIdx.x == 0) {
    unsigned gen = __hip_atomic_load(g, __ATOMIC_SEQ_CST, __HIP_MEMORY_SCOPE_AGENT);
    unsigned old = __hip_atomic_fetch_add(c, 1u, __ATOMIC_SEQ_CST, __HIP_MEMORY_SCOPE_AGENT);
    if (old == nblk - 1) {
      __hip_atomic_store(c, 0u, __ATOMIC_SEQ_CST, __HIP_MEMORY_SCOPE_AGENT);
      __hip_atomic_fetch_add(g, 1u, __ATOMIC_SEQ_CST, __HIP_MEMORY_SCOPE_AGENT);
    } else {
      while (__hip_atomic_load(g, __ATOMIC_SEQ_CST, __HIP_MEMORY_SCOPE_AGENT) == gen)
        __builtin_amdgcn_s_sleep(2);
    }
  }
  __syncthreads();
  __threadfence();  // acquire: invalidate stale cache lines
}

// ---- conv stage body (v6 structure) ------------------------------------------
// 512 thr = 8 waves = 4 wr x 2 kh; wave = 64oc x 64pix (row h0+wr) x K/2 (kh).
template <int CIN>
__device__ __forceinline__ void conv_body(
    const unsigned* __restrict__ in0, const unsigned* in1,
    const unsigned* __restrict__ wbase, const float* __restrict__ bias,
    float bmult, bool outf32, void* outp,
    unsigned* Alds, unsigned* WldsA, int tid, int bid) {
  constexpr int WPP = CIN / 2;          // u32 words per pixel
  constexpr int CHW = 64 * WPP;         // words per weight chunk
  constexpr int WL = CHW / 2048;        // gload_lds per thread per chunk
  constexpr int ROWW = 66 * WPP;        // words per staged act row
  constexpr int ACTW = 6 * ROWW;
  constexpr int ACT_U4 = ACTW / 4;
  constexpr int AJ = (ACT_U4 + 511) / 512;
  constexpr int KCW = CIN / 64;         // kc iterations per kh

  const int lane = tid & 63;
  const int wav = tid >> 6;
  const int wr = wav >> 1;
  const int kh = wav & 1;
  const int l15 = lane & 15, q = lane >> 4;
  const int n = bid & 7;
  const int ochalf = (bid >> 3) & 1;
  const int hq = bid >> 4;
  const int h0 = hq * 4;
  const bool dual = (in1 != nullptr);

  const unsigned* wb = wbase + (size_t)ochalf * 9 * CHW;

  // prologue: issue weight chunks 0,1 async into LDS bufs 0,1
#pragma unroll
  for (int s = 0; s < WL; ++s)
    gload16(wb + s * 2048 + tid * 4, &WldsA[0 * CHW + s * 2048 + wav * 256]);
#pragma unroll
  for (int s = 0; s < WL; ++s)
    gload16(wb + CHW + s * 2048 + tid * 4, &WldsA[1 * CHW + s * 2048 + wav * 256]);

  // stage acts once (6 padded rows, fused child-sum)
  {
    const size_t abase = ((size_t)n * 66 + h0) * ROWW;
    const uint4* g0 = (const uint4*)(in0 + abase);
    const uint4* g1 = (const uint4*)(in1 + abase);
#pragma unroll
    for (int j = 0; j < AJ; ++j) {
      int i = tid + j * 512;
      if (i < ACT_U4) {
        uint4 v = g0[i];
        if (dual) v = addpk4(v, g1[i]);
        *(uint4*)&Alds[4 * i] = v;
      }
    }
  }
  __syncthreads();

  f32x4 acc[4][4];
#pragma unroll
  for (int m = 0; m < 4; ++m)
#pragma unroll
    for (int p = 0; p < 4; ++p) acc[m][p] = (f32x4)0.f;

#pragma unroll
  for (int t = 0; t < 9; ++t) {
    if (t < 8) waitcnt_vm<WL>();
    else waitcnt_vm<0>();
    __builtin_amdgcn_s_barrier();
    __builtin_amdgcn_sched_barrier(0);

    const unsigned* WB = WldsA + (t % 3) * CHW;
    const int dy = t / 3, dx = t % 3;
    const int arow = (wr + dy) * 66;

    __builtin_amdgcn_s_setprio(1);
#pragma unroll
    for (int kc2 = 0; kc2 < KCW; ++kc2) {
      const int kc = kh * KCW + kc2;
      bf16x8 a[4];
#pragma unroll
      for (int m = 0; m < 4; ++m) {
        int r = m * 16 + l15;
        U4 u;
        u.u = *(const uint4*)&WB[r * WPP + ((kc * 16 + q * 4) ^ ((r & 7) << 2))];
        a[m] = u.b;
      }
      bf16x8 b[4];
#pragma unroll
      for (int p = 0; p < 4; ++p) {
        int col = p * 16 + l15 + dx;
        U4 u;
        u.u = *(const uint4*)&Alds[(arow + col) * WPP +
                                   ((kc * 16 + q * 4) ^ ((col & 7) << 2))];
        b[p] = u.b;
      }
#pragma unroll
      for (int m = 0; m < 4; ++m)
#pragma unroll
        for (int p = 0; p < 4; ++p)
          acc[m][p] =
              __builtin_amdgcn_mfma_f32_16x16x32_bf16(a[m], b[p], acc[m][p], 0, 0, 0);
    }
    __builtin_amdgcn_s_setprio(0);
    __builtin_amdgcn_sched_barrier(0);

    if (t + 2 < 9) {
#pragma unroll
      for (int s = 0; s < WL; ++s)
        gload16(wb + (size_t)(t + 2) * CHW + s * 2048 + tid * 4,
                &WldsA[((t + 2) % 3) * CHW + s * 2048 + wav * 256]);
    }
    __builtin_amdgcn_sched_barrier(0);
  }

  // K-pair reduction through LDS (acts dead)
  __syncthreads();
  float* R = (float*)Alds;
  if (kh) {
#pragma unroll
    for (int m = 0; m < 4; ++m)
#pragma unroll
      for (int p = 0; p < 4; ++p)
        *(f32x4*)&R[(wr * 16 + m * 4 + p) * 256 + lane * 4] = acc[m][p];
  }
  __syncthreads();
  if (!kh) {
#pragma unroll
    for (int m = 0; m < 4; ++m)
#pragma unroll
      for (int p = 0; p < 4; ++p) {
        f32x4 o = *(const f32x4*)&R[(wr * 16 + m * 4 + p) * 256 + lane * 4];
        acc[m][p] += o;
      }
    const int obase = ochalf * 64;
    if (outf32) {
      float* out = (float*)outp;
#pragma unroll
      for (int m = 0; m < 4; ++m) {
        int oc0 = obase + m * 16 + q * 4;
        float4 bb = *(const float4*)&bias[oc0];
#pragma unroll
        for (int p = 0; p < 4; ++p) {
          int w = p * 16 + l15;
#pragma unroll
          for (int j = 0; j < 4; ++j)
            out[(((size_t)n * 128 + oc0 + j) * 64 + (h0 + wr)) * 64 + w] =
                acc[m][p][j] + ((const float*)&bb)[j] * bmult;
        }
      }
    } else {
      unsigned* out = (unsigned*)outp;
#pragma unroll
      for (int m = 0; m < 4; ++m) {
        int oc0 = obase + m * 16 + q * 4;
        float4 bb = *(const float4*)&bias[oc0];
        int icp0 = oc0 >> 1;
#pragma unroll
        for (int p = 0; p < 4; ++p) {
          int w = p * 16 + l15;
          int wp = w + 1;
          unsigned lo = pk_bf16(acc[m][p][0] + bb.x * bmult, acc[m][p][1] + bb.y * bmult);
          unsigned hi = pk_bf16(acc[m][p][2] + bb.z * bmult, acc[m][p][3] + bb.w * bmult);
          int pos = icp0 ^ ((wp & 7) << 2);
          size_t base = (((size_t)n * 66 + (h0 + 1 + wr)) * 66 + wp) * 64;
          *(uint2*)&out[base + pos] = make_uint2(lo, hi);
        }
      }
    }
  }
}

// ---- the single persistent kernel --------------------------------------------
__global__ __launch_bounds__(512, 2) void mega(
    const float* __restrict__ x, const float* __restrict__ W0,
    const float* __restrict__ b0, const float* __restrict__ Wn,
    const float* __restrict__ bn, float* __restrict__ out,
    unsigned* __restrict__ B0, unsigned* __restrict__ B1,
    unsigned* __restrict__ B2, unsigned* __restrict__ T,
    unsigned* __restrict__ Wb, unsigned* __restrict__ bar) {
  __shared__ unsigned Alds[25344];      // 101.4 KB (acts / xl / reduction)
  __shared__ unsigned Wlds[3 * 4096];   // 49.2 KB (3-deep weight pipeline)

  const int tid = threadIdx.x;
  const int bid = blockIdx.x;
  const int n = bid & 7;

  // ---- setup a: repack weights fp32 OIHW -> swizzled bf16 chunks ----
  // stem: 18 chunks (ochalf*9+tap) of [64r][32w]; node s: 18 of [64r][64w]
  // at 36864 + s*73728.  Wb[ch][r*W + j] = w(r, icpair=j^((r&7)<<2), tap).
#pragma unroll
  for (int it = 0; it < 4; ++it) {
    unsigned gid = (unsigned)bid * 512 + tid + it * 131072u;
    if (gid < WB_WORDS) {
      const float* src;
      int CIN, c, r, j;
      if (gid < 36864) {
        src = W0; CIN = 64;
        c = gid >> 11; int w = gid & 2047; r = w >> 5; j = w & 31;
      } else {
        unsigned g2 = gid - 36864;
        int s = g2 / 73728; unsigned r2 = g2 % 73728;
        src = Wn + (size_t)s * 147456; CIN = 128;
        c = r2 >> 12; int w = r2 & 4095; r = w >> 6; j = w & 63;
      }
      int ochalf = c / 9, tap = c % 9;
      int dy = tap / 3, dx = tap % 3;
      int icpair = j ^ ((r & 7) << 2);
      int oc = ochalf * 64 + r;
      size_t base = (((size_t)oc * CIN + 2 * icpair) * 3 + dy) * 3 + dx;
      Wb[gid] = pk_bf16(src[base], src[base + 9]);
    }
  }

  // ---- setup b: zero halo rings ----
  {
    unsigned gid = (unsigned)bid * 512 + tid;
    if (gid < 116480) {
      unsigned* buf; int CW; unsigned u;
      if (gid < 99840) {
        buf = gid < 33280 ? B0 : (gid < 66560 ? B1 : B2);
        u = gid % 33280; CW = 64;
      } else {
        buf = T; u = gid - 99840; CW = 32;
      }
      int per_n = 65 * CW;
      int nn = u / per_n;
      unsigned v = u % per_n;
      int pix = (v * 4) / CW, cw = (v * 4) % CW;
      int row, col;
      if (pix < 66) { row = 0; col = pix; }
      else if (pix < 132) { row = 65; col = pix - 66; }
      else if (pix < 196) { row = pix - 131; col = 0; }
      else { row = pix - 195; col = 65; }
      *(uint4*)&buf[((((size_t)nn * 66 + row) * 66 + col) * CW) + cw] =
          make_uint4(0, 0, 0, 0);
    }
  }

  // ---- setup c: transform x fp32 NCHW -> bf16 padded swizzled (64ch) ----
  {
    float* xl = (float*)Alds;           // [2][64][65]
    int hh = bid >> 3;                  // 0..31
    int sub = tid >> 8;                 // 0..1
    int t8 = tid & 255;
    int h = hh * 2 + sub;
#pragma unroll
    for (int k = 0; k < 16; ++k) {
      int idx = t8 + k * 256;
      int ic = idx >> 6, w = idx & 63;
      xl[(sub * 64 + w) * 65 + ic] = x[(((size_t)n * 64 + ic) * 64 + h) * 64 + w];
    }
    __syncthreads();
#pragma unroll
    for (int k = 0; k < 8; ++k) {
      int idx = t8 + k * 256;
      int w = idx >> 5, icp = idx & 31;
      unsigned v = pk_bf16(xl[(sub * 64 + w) * 65 + icp * 2],
                           xl[(sub * 64 + w) * 65 + icp * 2 + 1]);
      int wp = w + 1;
      int pos = icp ^ ((wp & 7) << 2);
      T[(((size_t)n * 66 + (h + 1)) * 66 + wp) * 32 + pos] = v;
    }
  }

  grid_bar(bar + 0, bar + 64, 256);     // global: Wb/T/halos ready

  // ---- stem: T -> B0 (CIN=64) ----
  conv_body<64>(T, nullptr, Wb, b0, 1.f, false, B0, Alds, Wlds, tid, bid);
  grid_bar(bar + 8 + n, bar + 72 + n, 32);

  // ---- nodes 1..6 ----
  const unsigned* i0t[6] = {B0, B0, B1, B2, B0, B1};
  const unsigned* i1t[6] = {nullptr, B1, B2, B0, B1, B2};
  unsigned* ot[6] = {B1, B2, B0, B1, B2, (unsigned*)out};
#pragma unroll 1
  for (int s = 0; s < 6; ++s) {
    conv_body<128>(i0t[s], i1t[s], Wb + 36864 + (size_t)s * 73728, bn + s * 128,
                   s == 0 ? 1.f : 2.f, s == 5, ot[s], Alds, Wlds, tid, bid);
    if (s < 5) grid_bar(bar + (s + 2) * 8 + n, bar + 64 + (s + 2) * 8 + n, 32);
  }
}

// ---------------- launch ------------------------------------------------------
extern "C" void kernel_launch(void* const* d_in, const int* in_sizes, int n_in,
                              void* d_out, int out_size, void* d_ws,
                              size_t ws_size, hipStream_t stream) {
  const float* x = (const float*)d_in[0];
  const float* W0 = (const float*)d_in[1];
  const float* b0 = (const float*)d_in[2];
  const float* Wn = (const float*)d_in[3];
  const float* bn = (const float*)d_in[4];

  const size_t ACTB = (size_t)8 * 66 * 66 * 64;  // words per 128-ch act buffer
  const size_t TW = (size_t)8 * 66 * 66 * 32;    // words for 64-ch stem input
  unsigned* B0 = (unsigned*)d_ws;
  unsigned* B1 = B0 + ACTB;
  unsigned* B2 = B1 + ACTB;
  unsigned* T = B2 + ACTB;
  unsigned* Wb = T + TW;
  unsigned* bar = Wb + WB_WORDS;

  hipMemsetAsync(bar, 0, 128 * sizeof(unsigned), stream);  // barrier state
  mega<<<256, 512, 0, stream>>>(x, W0, b0, Wn, bn, (float*)d_out,
                                B0, B1, B2, T, Wb, bar);

  (void)in_sizes; (void)n_in; (void)out_size; (void)ws_size;
}

// Round 8
// 108.368 us; speedup vs baseline: 7.1935x; 7.1935x over previous
//
#include <hip/hip_runtime.h>

// GraphConvBlock, v8 = v6 (best verified: 115us) + two consolidations:
//  (1) single fused setup kernel (repack + halo-zero + transform_x): 10 -> 8 dispatches
//  (2) act staging split: rows 0-3 before phase 0; rows 4-5 reg-loaded up front,
//      committed to LDS at tail of phase 0 (first read at t=3). Phase waits gain
//      lgkmcnt(0) so raw s_barrier seals the ds_writes.
// Inner conv structure unchanged: bf16 MFMA implicit GEMM, K-split wave pairs,
// 3-deep async weight LDS pipeline (global_load_lds + counted vmcnt).

typedef __bf16 bf16x8 __attribute__((ext_vector_type(8)));
typedef float f32x4 __attribute__((ext_vector_type(4)));

union U4 { uint4 u; bf16x8 b; };

__device__ inline unsigned pk_bf16(float lo, float hi) {
  unsigned r;
  asm volatile("v_cvt_pk_bf16_f32 %0, %1, %2" : "=v"(r) : "v"(lo), "v"(hi));
  return r;
}

__device__ inline unsigned addpk(unsigned a, unsigned b) {
  float alo = __builtin_bit_cast(float, a << 16);
  float ahi = __builtin_bit_cast(float, a & 0xFFFF0000u);
  float blo = __builtin_bit_cast(float, b << 16);
  float bhi = __builtin_bit_cast(float, b & 0xFFFF0000u);
  return pk_bf16(alo + blo, ahi + bhi);
}

__device__ inline uint4 addpk4(uint4 a, uint4 b) {
  return make_uint4(addpk(a.x, b.x), addpk(a.y, b.y), addpk(a.z, b.z), addpk(a.w, b.w));
}

__device__ __forceinline__ void gload16(const unsigned* g, unsigned* l) {
  __builtin_amdgcn_global_load_lds(
      (const __attribute__((address_space(1))) unsigned*)(g),
      (__attribute__((address_space(3))) unsigned*)(l), 16, 0, 0);
}

template <int N>
__device__ __forceinline__ void waitcnt_vm_lgkm() {
  if constexpr (N == 0)
    asm volatile("s_waitcnt vmcnt(0) lgkmcnt(0)" ::: "memory");
  else if constexpr (N == 1)
    asm volatile("s_waitcnt vmcnt(1) lgkmcnt(0)" ::: "memory");
  else
    asm volatile("s_waitcnt vmcnt(2) lgkmcnt(0)" ::: "memory");
}

#define WB_WORDS 479232

// ---------------- fused setup kernel -----------------------------------------
// grid 256 x 512. (a) repack weights fp32 OIHW -> swizzled bf16 chunks;
// (b) zero halo rings of B0/B1/B2/T; (c) transform x -> bf16 padded swizzled T.
__global__ __launch_bounds__(512) void setup_all(
    const float* __restrict__ x, const float* __restrict__ W0,
    const float* __restrict__ Wn, unsigned* __restrict__ B0,
    unsigned* __restrict__ B1, unsigned* __restrict__ B2,
    unsigned* __restrict__ T, unsigned* __restrict__ Wb) {
  __shared__ float xl[2 * 64 * 65];
  const int tid = threadIdx.x;
  const int bid = blockIdx.x;
  const int n = bid & 7;

  // (a) repack: stem 18 chunks [64r][32w]; node s: 18 chunks [64r][64w] at
  // 36864+s*73728.  Wb[ch][r*W + j] = w(oc, icpair=j^((r&7)<<2), tap).
#pragma unroll
  for (int it = 0; it < 4; ++it) {
    unsigned gid = (unsigned)bid * 512 + tid + it * 131072u;
    if (gid < WB_WORDS) {
      const float* src;
      int CIN, c, r, j;
      if (gid < 36864) {
        src = W0; CIN = 64;
        c = gid >> 11; int w = gid & 2047; r = w >> 5; j = w & 31;
      } else {
        unsigned g2 = gid - 36864;
        int s = g2 / 73728; unsigned r2 = g2 % 73728;
        src = Wn + (size_t)s * 147456; CIN = 128;
        c = r2 >> 12; int w = r2 & 4095; r = w >> 6; j = w & 63;
      }
      int ochalf = c / 9, tap = c % 9;
      int dy = tap / 3, dx = tap % 3;
      int icpair = j ^ ((r & 7) << 2);
      int oc = ochalf * 64 + r;
      size_t base = (((size_t)oc * CIN + 2 * icpair) * 3 + dy) * 3 + dx;
      Wb[gid] = pk_bf16(src[base], src[base + 9]);
    }
  }

  // (b) zero halo rings
  {
    unsigned gid = (unsigned)bid * 512 + tid;
    if (gid < 116480) {
      unsigned* buf; int CW; unsigned u;
      if (gid < 99840) {
        buf = gid < 33280 ? B0 : (gid < 66560 ? B1 : B2);
        u = gid % 33280; CW = 64;
      } else {
        buf = T; u = gid - 99840; CW = 32;
      }
      int per_n = 65 * CW;
      int nn = u / per_n;
      unsigned v = u % per_n;
      int pix = (v * 4) / CW, cw = (v * 4) % CW;
      int row, col;
      if (pix < 66) { row = 0; col = pix; }
      else if (pix < 132) { row = 65; col = pix - 66; }
      else if (pix < 196) { row = pix - 131; col = 0; }
      else { row = pix - 195; col = 65; }
      *(uint4*)&buf[((((size_t)nn * 66 + row) * 66 + col) * CW) + cw] =
          make_uint4(0, 0, 0, 0);
    }
  }

  // (c) transform x: block handles rows 2*hh, 2*hh+1 of image n
  {
    int hh = bid >> 3;                  // 0..31
    int sub = tid >> 8;                 // 0..1
    int t8 = tid & 255;
    int h = hh * 2 + sub;
#pragma unroll
    for (int k = 0; k < 16; ++k) {
      int idx = t8 + k * 256;
      int ic = idx >> 6, w = idx & 63;
      xl[(sub * 64 + w) * 65 + ic] = x[(((size_t)n * 64 + ic) * 64 + h) * 64 + w];
    }
    __syncthreads();
#pragma unroll
    for (int k = 0; k < 8; ++k) {
      int idx = t8 + k * 256;
      int w = idx >> 5, icp = idx & 31;
      unsigned v = pk_bf16(xl[(sub * 64 + w) * 65 + icp * 2],
                           xl[(sub * 64 + w) * 65 + icp * 2 + 1]);
      int wp = w + 1;
      int pos = icp ^ ((wp & 7) << 2);
      T[(((size_t)n * 66 + (h + 1)) * 66 + wp) * 32 + pos] = v;
    }
  }
}

// ---------------- main conv stage --------------------------------------------
// 512 thr = 8 waves = 4 wr x 2 kh. Wave: 64oc x 64pix (row h0+wr) x K/2 (kh).
// Pair (wr,kh=0/1) reduces via LDS. grid 256 = 2 ochalf x 8 n x 16 hq.
template <int CIN, bool DUAL, bool OUTF32>
__global__ __launch_bounds__(512, 2) void conv_stage(
    const unsigned* __restrict__ in0, const unsigned* __restrict__ in1,
    const unsigned* __restrict__ wb, const float* __restrict__ bias,
    float bmult, void* __restrict__ outp) {
  constexpr int WPP = CIN / 2;          // u32 words per pixel
  constexpr int CHW = 64 * WPP;         // words per weight chunk (full-K, 64 oc)
  constexpr int WL = CHW / 2048;        // gload_lds per thread per chunk (512t)
  constexpr int ROWW = 66 * WPP;        // words per staged act row
  constexpr int ACTW = 6 * ROWW;
  constexpr int ALDS_W = (ACTW > 16384) ? ACTW : 16384;  // also reduction buf
  constexpr int R4_U4 = 4 * ROWW / 4;   // uint4 in rows 0..3
  constexpr int R2_U4 = 2 * ROWW / 4;   // uint4 in rows 4..5
  constexpr int AJ4 = (R4_U4 + 511) / 512;
  constexpr int LJ = (R2_U4 + 511) / 512;
  constexpr int KCW = CIN / 64;         // kc iterations per kh

  __shared__ unsigned Alds[ALDS_W];
  __shared__ unsigned Wlds[3][CHW];

  const int tid = threadIdx.x;
  const int lane = tid & 63;
  const int wav = tid >> 6;             // 0..7
  const int wr = wav >> 1;              // output row 0..3
  const int kh = wav & 1;               // K half
  const int l15 = lane & 15, q = lane >> 4;
  const int bid = blockIdx.x;
  const int n = bid & 7;                // same-n -> same XCD (L2 locality)
  const int ochalf = (bid >> 3) & 1;
  const int hq = bid >> 4;              // 0..15
  const int h0 = hq * 4;

  const unsigned* wbase = wb + (size_t)ochalf * 9 * CHW;
  const size_t abase = ((size_t)n * 66 + h0) * ROWW;
  const uint4* g0 = (const uint4*)(in0 + abase);
  const uint4* g1 = (const uint4*)(in1 + abase);

  // ---- issue reg-loads for act rows 4,5 FIRST (oldest in vmcnt queue) ----
  uint4 l0[LJ], l1[LJ];
#pragma unroll
  for (int j = 0; j < LJ; ++j) {
    int i = tid + j * 512;
    if (i < R2_U4) {
      l0[j] = g0[R4_U4 + i];
      if (DUAL) l1[j] = g1[R4_U4 + i];
    }
  }

  // ---- prologue: issue weight chunks 0,1 (async, direct to LDS) ----
#pragma unroll
  for (int s = 0; s < WL; ++s)
    gload16(wbase + s * 2048 + tid * 4, &Wlds[0][s * 2048 + wav * 256]);
#pragma unroll
  for (int s = 0; s < WL; ++s)
    gload16(wbase + CHW + s * 2048 + tid * 4, &Wlds[1][s * 2048 + wav * 256]);

  // ---- stage act rows 0..3 (fused child-sum) ----
#pragma unroll
  for (int j = 0; j < AJ4; ++j) {
    int i = tid + j * 512;
    if (i < R4_U4) {
      uint4 v = g0[i];
      if (DUAL) v = addpk4(v, g1[i]);
      *(uint4*)&Alds[4 * i] = v;
    }
  }
  __syncthreads();  // rows 0..3 visible

  f32x4 acc[4][4];
#pragma unroll
  for (int m = 0; m < 4; ++m)
#pragma unroll
    for (int p = 0; p < 4; ++p) acc[m][p] = (f32x4)0.f;

#pragma unroll
  for (int t = 0; t < 9; ++t) {
    // chunk t landed (steady state: chunk t+1's WL loads stay in flight);
    // lgkmcnt(0) seals any pending ds_writes before the raw barrier.
    if (t < 8) waitcnt_vm_lgkm<WL>();
    else waitcnt_vm_lgkm<0>();
    __builtin_amdgcn_s_barrier();
    __builtin_amdgcn_sched_barrier(0);

    const unsigned* WB = Wlds[t % 3];
    const int dy = t / 3, dx = t % 3;
    const int arow = (wr + dy) * 66;

    __builtin_amdgcn_s_setprio(1);
#pragma unroll
    for (int kc2 = 0; kc2 < KCW; ++kc2) {
      const int kc = kh * KCW + kc2;
      bf16x8 a[4];
#pragma unroll
      for (int m = 0; m < 4; ++m) {
        int r = m * 16 + l15;
        U4 u;
        u.u = *(const uint4*)&WB[r * WPP + ((kc * 16 + q * 4) ^ ((r & 7) << 2))];
        a[m] = u.b;
      }
      bf16x8 b[4];
#pragma unroll
      for (int p = 0; p < 4; ++p) {
        int col = p * 16 + l15 + dx;
        U4 u;
        u.u = *(const uint4*)&Alds[(arow + col) * WPP +
                                   ((kc * 16 + q * 4) ^ ((col & 7) << 2))];
        b[p] = u.b;
      }
#pragma unroll
      for (int m = 0; m < 4; ++m)
#pragma unroll
        for (int p = 0; p < 4; ++p)
          acc[m][p] =
              __builtin_amdgcn_mfma_f32_16x16x32_bf16(a[m], b[p], acc[m][p], 0, 0, 0);
    }
    __builtin_amdgcn_s_setprio(0);
    __builtin_amdgcn_sched_barrier(0);

    // tail of phase 0: commit act rows 4,5 (first read at t=3; sealed by the
    // t=1 barrier's lgkmcnt(0)).
    if (t == 0) {
#pragma unroll
      for (int j = 0; j < LJ; ++j) {
        int i = tid + j * 512;
        if (i < R2_U4) {
          uint4 v = l0[j];
          if (DUAL) v = addpk4(v, l1[j]);
          *(uint4*)&Alds[4 * (R4_U4 + i)] = v;
        }
      }
    }

    // issue chunk t+2 into buffer (t+2)%3 == (t-1)%3, whose readers finished
    // before THIS phase's barrier -> race-free with a single barrier/phase.
    if (t + 2 < 9) {
#pragma unroll
      for (int s = 0; s < WL; ++s)
        gload16(wbase + (size_t)(t + 2) * CHW + s * 2048 + tid * 4,
                &Wlds[(t + 2) % 3][s * 2048 + wav * 256]);
    }
    __builtin_amdgcn_sched_barrier(0);
  }

  // ---- K-pair reduction through LDS (reuse Alds; acts dead) ----
  __syncthreads();  // all phase-8 LDS reads done before overwrite
  float* R = (float*)Alds;
  if (kh) {
#pragma unroll
    for (int m = 0; m < 4; ++m)
#pragma unroll
      for (int p = 0; p < 4; ++p)
        *(f32x4*)&R[(wr * 16 + m * 4 + p) * 256 + lane * 4] = acc[m][p];
  }
  __syncthreads();
  if (kh) return;
#pragma unroll
  for (int m = 0; m < 4; ++m)
#pragma unroll
    for (int p = 0; p < 4; ++p) {
      f32x4 o = *(const f32x4*)&R[(wr * 16 + m * 4 + p) * 256 + lane * 4];
      acc[m][p] += o;
    }

  // ---- epilogue (kh==0 waves) ----
  const int obase = ochalf * 64;
  if (OUTF32) {
    float* out = (float*)outp;
#pragma unroll
    for (int m = 0; m < 4; ++m) {
      int oc0 = obase + m * 16 + q * 4;
      float4 bb = *(const float4*)&bias[oc0];
#pragma unroll
      for (int p = 0; p < 4; ++p) {
        int w = p * 16 + l15;
#pragma unroll
        for (int j = 0; j < 4; ++j)
          out[(((size_t)n * 128 + oc0 + j) * 64 + (h0 + wr)) * 64 + w] =
              acc[m][p][j] + ((const float*)&bb)[j] * bmult;
      }
    }
  } else {
    unsigned* out = (unsigned*)outp;
#pragma unroll
    for (int m = 0; m < 4; ++m) {
      int oc0 = obase + m * 16 + q * 4;
      float4 bb = *(const float4*)&bias[oc0];
      int icp0 = oc0 >> 1;
#pragma unroll
      for (int p = 0; p < 4; ++p) {
        int w = p * 16 + l15;
        int wp = w + 1;
        unsigned lo = pk_bf16(acc[m][p][0] + bb.x * bmult, acc[m][p][1] + bb.y * bmult);
        unsigned hi = pk_bf16(acc[m][p][2] + bb.z * bmult, acc[m][p][3] + bb.w * bmult);
        int pos = icp0 ^ ((wp & 7) << 2);
        size_t base = (((size_t)n * 66 + (h0 + 1 + wr)) * 66 + wp) * 64;
        *(uint2*)&out[base + pos] = make_uint2(lo, hi);
      }
    }
  }
}

// ---------------- launch ------------------------------------------------------
extern "C" void kernel_launch(void* const* d_in, const int* in_sizes, int n_in,
                              void* d_out, int out_size, void* d_ws,
                              size_t ws_size, hipStream_t stream) {
  const float* x = (const float*)d_in[0];
  const float* W0 = (const float*)d_in[1];
  const float* b0 = (const float*)d_in[2];
  const float* Wn = (const float*)d_in[3];
  const float* bn = (const float*)d_in[4];

  const size_t ACTB = (size_t)8 * 66 * 66 * 64;  // words per 128-ch act buffer
  const size_t TW = (size_t)8 * 66 * 66 * 32;    // words for 64-ch stem input
  unsigned* B0 = (unsigned*)d_ws;
  unsigned* B1 = B0 + ACTB;
  unsigned* B2 = B1 + ACTB;
  unsigned* T = B2 + ACTB;
  unsigned* Wb = T + TW;

  setup_all<<<256, 512, 0, stream>>>(x, W0, Wn, B0, B1, B2, T, Wb);

  dim3 grid(256), blk(512);
  const unsigned* Wnode = Wb + 36864;
  const size_t NW = 73728;  // words per node-stage weight block

  // stem: T -> B0
  conv_stage<64, false, false><<<grid, blk, 0, stream>>>(T, T, Wb, b0, 1.f, B0);
  // node1 {0}: B0 -> B1
  conv_stage<128, false, false><<<grid, blk, 0, stream>>>(B0, B0, Wnode, bn + 0, 1.f, B1);
  // node2 {0,1}: B0+B1 -> B2
  conv_stage<128, true, false><<<grid, blk, 0, stream>>>(B0, B1, Wnode + 1 * NW, bn + 128, 2.f, B2);
  // node3 {1,2}: B1+B2 -> B0
  conv_stage<128, true, false><<<grid, blk, 0, stream>>>(B1, B2, Wnode + 2 * NW, bn + 256, 2.f, B0);
  // node4 {2,3}: B2+B0 -> B1
  conv_stage<128, true, false><<<grid, blk, 0, stream>>>(B2, B0, Wnode + 3 * NW, bn + 384, 2.f, B1);
  // node5 {3,4}: B0+B1 -> B2
  conv_stage<128, true, false><<<grid, blk, 0, stream>>>(B0, B1, Wnode + 4 * NW, bn + 512, 2.f, B2);
  // node6 {4,5}: B1+B2 -> d_out (fp32 NCHW)
  conv_stage<128, true, true><<<grid, blk, 0, stream>>>(B1, B2, Wnode + 5 * NW, bn + 640, 2.f, d_out);

  (void)in_sizes; (void)n_in; (void)out_size; (void)ws_size;
}